// Round 13
// baseline (396.525 us; speedup 1.0000x reference)
//
#include <hip/hip_runtime.h>
#include <hip/hip_bf16.h>

// Problem constants (shapes fixed by reference)
#define FP 48   // F*P = 4*12 floats per node
#define HID 64
#define NP 12   // periods
#define NF 4    // input feats
#define SCAN_B 1024
#define PL 65      // padded LDS stride for prep tiles
#define CH_LOG 14  // edges per hist chunk = 16384
#define CH (1 << CH_LOG)
#define NW 25024   // LDS u32 words for paired-u16 counters (supports N <= 50048)

// ---------------------------------------------------------------------------
// prep helpers: register-tiled 64x64 @ 64x64 (A in LDS stride-65, B global)
// ---------------------------------------------------------------------------
__device__ __forceinline__ void mm_stage(const float* __restrict__ Alds,
                                         const float* __restrict__ Wg,
                                         float* __restrict__ Clds, int t)
{
    const int rg = (t >> 4) * 4, cg = (t & 15) * 4;
    float acc[4][4] = {};
    for (int k = 0; k < 64; ++k) {
        float a0 = Alds[(rg + 0) * PL + k];
        float a1 = Alds[(rg + 1) * PL + k];
        float a2 = Alds[(rg + 2) * PL + k];
        float a3 = Alds[(rg + 3) * PL + k];
        const float4 bv = *reinterpret_cast<const float4*>(Wg + k * 64 + cg);
        acc[0][0] += a0 * bv.x; acc[0][1] += a0 * bv.y; acc[0][2] += a0 * bv.z; acc[0][3] += a0 * bv.w;
        acc[1][0] += a1 * bv.x; acc[1][1] += a1 * bv.y; acc[1][2] += a1 * bv.z; acc[1][3] += a1 * bv.w;
        acc[2][0] += a2 * bv.x; acc[2][1] += a2 * bv.y; acc[2][2] += a2 * bv.z; acc[2][3] += a2 * bv.w;
        acc[3][0] += a3 * bv.x; acc[3][1] += a3 * bv.y; acc[3][2] += a3 * bv.z; acc[3][3] += a3 * bv.w;
    }
    for (int i = 0; i < 4; ++i)
        for (int j = 0; j < 4; ++j)
            Clds[(rg + i) * PL + cg + j] = acc[i][j];
}

__device__ __forceinline__ void bias_stage(const float* __restrict__ bin,
                                           const float* __restrict__ Wg,
                                           const float* __restrict__ badd,
                                           float* __restrict__ bout, int t)
{
    if (t < 64) {
        float s = badd[t];
        for (int k = 0; k < 64; ++k) s += bin[k] * Wg[k * 64 + t];
        bout[t] = s;
    }
}

// bf16 round-to-nearest-even (x ~ N(0,1): no inf/nan concerns)
__device__ __forceinline__ unsigned short f2bf(float v)
{
    unsigned u = __float_as_uint(v);
    return (unsigned short)((u + 0x7fffu + ((u >> 16) & 1u)) >> 16);
}

// ---------------------------------------------------------------------------
// fused init + prep: block 0 does the weight-collapse prep; blocks >=1 init
// deg[n]=1.0 (self-loop), zero the edge pad, and convert x fp32 -> bf16 rows
// (96B/row) so the gather working set (4.8MB) is L2-resident.
// r-gate params provably unused (H=0 => Hz*r = 0).
// ---------------------------------------------------------------------------
__global__ __launch_bounds__(256) void init_prep_kernel(
    const float* __restrict__ att,
    const float* __restrict__ Wg_z, const float* __restrict__ bg_z,
    const float* __restrict__ Wl_z, const float* __restrict__ bl_z,
    const float* __restrict__ Wg_h, const float* __restrict__ bg_h,
    const float* __restrict__ Wl_h, const float* __restrict__ bl_h,
    const float* __restrict__ W1, const float* __restrict__ b1,
    const float* __restrict__ W2, const float* __restrict__ b2,
    const float* __restrict__ W3, const float* __restrict__ b3,
    const float* __restrict__ W4, const float* __restrict__ b4,
    const float* __restrict__ Wo, const float* __restrict__ bo,
    float* __restrict__ probs, float* __restrict__ Mz, float* __restrict__ cz,
    float* __restrict__ Mh, float* __restrict__ ch,
    float* __restrict__ Wc, float* __restrict__ bc,
    float* __restrict__ deg, int2* __restrict__ edgepad,
    const float* __restrict__ x, unsigned short* __restrict__ xs,
    int N, int nblk)
{
    const int t = threadIdx.x;

    if (blockIdx.x > 0) {
        int i = (blockIdx.x - 1) * 256 + t;
        if (i < N) deg[i] = 1.0f;            // self-loop weight
        if (blockIdx.x == 1 && t < 16) edgepad[t] = make_int2(0, 0);
        const int nq = N * (FP / 4);
        const int stride = nblk * 256;
        for (int j = (blockIdx.x - 1) * 256 + t; j < nq; j += stride) {
            const float4 v = *reinterpret_cast<const float4*>(x + j * 4);
            ushort4 o;
            o.x = f2bf(v.x); o.y = f2bf(v.y); o.z = f2bf(v.z); o.w = f2bf(v.w);
            *reinterpret_cast<ushort4*>(xs + j * 4) = o;
        }
        return;
    }

    __shared__ float A[64 * PL];
    __shared__ float B[64 * PL];
    __shared__ float bias[64];
    __shared__ float bias2[64];

    if (t == 0) {
        float m = att[0];
        for (int p = 1; p < NP; ++p) m = fmaxf(m, att[p]);
        float e[NP]; float s = 0.f;
        for (int p = 0; p < NP; ++p) { e[p] = __expf(att[p] - m); s += e[p]; }
        float inv = 1.f / s;
        for (int p = 0; p < NP; ++p) probs[p] = e[p] * inv;
    }

    // gate matrices: Mz/Mh 4x64; thread t -> (f=t>>6, j=t&63)
    {
        int f = t >> 6, j = t & 63;
        float az = 0.f, ah = 0.f;
        for (int k = 0; k < HID; ++k) {
            az += Wg_z[f * HID + k] * Wl_z[k * HID + j];
            ah += Wg_h[f * HID + k] * Wl_h[k * HID + j];
        }
        Mz[t] = az; Mh[t] = ah;
    }
    if (t < HID) {
        float az = bl_z[t], ah = bl_h[t];
        for (int k = 0; k < HID; ++k) {
            az += bg_z[k] * Wl_z[k * HID + t];
            ah += bg_h[k] * Wl_h[k * HID + t];
        }
        cz[t] = az; ch[t] = ah;
    }

    for (int idx = t; idx < 4096; idx += 256) {
        int i = idx >> 6, j = idx & 63;
        A[i * PL + j] = W1[idx];
    }
    if (t < 64) bias[t] = b1[t];
    __syncthreads();

    mm_stage(A, W2, B, t);                 // B = W1@W2
    bias_stage(bias, W2, b2, bias2, t);    // bias2 = b1@W2 + b2
    __syncthreads();
    mm_stage(B, W3, A, t);                 // A = (W1W2)@W3
    bias_stage(bias2, W3, b3, bias, t);
    __syncthreads();
    mm_stage(A, W4, B, t);                 // B = (W1W2W3)@W4
    bias_stage(bias, W4, b4, bias2, t);
    __syncthreads();

    // final: Wc = B @ Wo (64x48), bc = bias2@Wo + bo
    {
        const int rg = (t >> 4) * 4, cg = (t & 15) * 4;
        if (cg < FP) {
            float acc[4][4] = {};
            for (int k = 0; k < 64; ++k) {
                float a0 = B[(rg + 0) * PL + k];
                float a1 = B[(rg + 1) * PL + k];
                float a2 = B[(rg + 2) * PL + k];
                float a3 = B[(rg + 3) * PL + k];
                const float4 bv = *reinterpret_cast<const float4*>(Wo + k * FP + cg);
                acc[0][0] += a0 * bv.x; acc[0][1] += a0 * bv.y; acc[0][2] += a0 * bv.z; acc[0][3] += a0 * bv.w;
                acc[1][0] += a1 * bv.x; acc[1][1] += a1 * bv.y; acc[1][2] += a1 * bv.z; acc[1][3] += a1 * bv.w;
                acc[2][0] += a2 * bv.x; acc[2][1] += a2 * bv.y; acc[2][2] += a2 * bv.z; acc[2][3] += a2 * bv.w;
                acc[3][0] += a3 * bv.x; acc[3][1] += a3 * bv.y; acc[3][2] += a3 * bv.z; acc[3][3] += a3 * bv.w;
            }
            for (int i = 0; i < 4; ++i)
                for (int j = 0; j < 4; ++j)
                    Wc[(rg + i) * FP + cg + j] = acc[i][j];
        }
        if (t < FP) {
            float s = bo[t];
            for (int k = 0; k < 64; ++k) s += bias2[k] * Wo[k * FP + t];
            bc[t] = s;
        }
    }
}

// ---------------------------------------------------------------------------
// hist v2: per-chunk LDS counting histogram (paired u16 in u32 words) — zero
// returned global atomics. Block c owns edges [c*CH, (c+1)*CH); ds_add_rtn
// gives each edge's in-chunk per-dst rank. Chunk counts stream out coalesced.
// The ew degree-sum is a NO-RETURN global float atomicAdd (R1-measured ~78G/s
// vs 19.5G/s for the old returned-atomic hist — the return dep + 200KB
// footprint contention was the R10-R12 hist bottleneck).
// Field safety: in-chunk per-dst count <= CH=16384 < 2^16, even adversarially.
// ---------------------------------------------------------------------------
__global__ __launch_bounds__(1024) void hist_kernel(
    const int* __restrict__ dst, const float* __restrict__ ew,
    float* __restrict__ deg, unsigned* __restrict__ chunkCnt,
    int* __restrict__ rank, int E)
{
    __shared__ unsigned sh[NW];
    const int t = threadIdx.x;
    for (int i = t; i < NW; i += 1024) sh[i] = 0u;
    __syncthreads();

    const int c    = blockIdx.x;
    const int base = c << CH_LOG;
    const int lim  = min(base + CH, E);
    for (int e = base + t; e < lim; e += 1024) {
        int d = dst[e];
        atomicAdd(&deg[d], ew[e]);                           // no-return
        unsigned sf  = (d & 1) ? 16u : 0u;
        unsigned old = atomicAdd(&sh[d >> 1], 1u << sf);     // ds_add_rtn
        rank[e] = (int)((old >> sf) & 0xFFFFu);
    }
    __syncthreads();

    unsigned* out = chunkCnt + (size_t)c * NW;
    for (int i = t; i < NW; i += 1024) out[i] = sh[i];
}

// ---------------------------------------------------------------------------
// chunkpre: per dst d, exclusive prefix of counts over chunks ->
// chunkPre[c][d], and total[d]. Thread-per-d; reads/writes coalesced across
// threads for each fixed c.
// ---------------------------------------------------------------------------
__global__ __launch_bounds__(1024) void chunkpre_kernel(
    const unsigned* __restrict__ chunkCnt, unsigned* __restrict__ chunkPre,
    int* __restrict__ total, int N, int nchunks)
{
    int d = blockIdx.x * 1024 + threadIdx.x;
    if (d >= N) return;
    const unsigned sf = (d & 1) ? 16u : 0u;
    const int w = d >> 1;
    unsigned run = 0;
    for (int c = 0; c < nchunks; ++c) {
        unsigned v = (chunkCnt[(size_t)c * NW + w] >> sf) & 0xFFFFu;
        chunkPre[(size_t)c * N + d] = run;
        run += v;
    }
    total[d] = (int)run;
}

// ---------------------------------------------------------------------------
// fused scan over total[]: block b sums all predecessor counts (coalesced),
// then local Hillis-Steele scan -> rowstart. Also dinv = rsqrt(deg).
// ---------------------------------------------------------------------------
__global__ __launch_bounds__(SCAN_B) void scan_kernel(const int* __restrict__ total,
                                                      const float* __restrict__ deg,
                                                      int* __restrict__ rowstart,
                                                      float* __restrict__ dinv, int N)
{
    __shared__ int red[SCAN_B];
    __shared__ int sdata[SCAN_B];
    const int t = threadIdx.x;
    const int base = blockIdx.x * SCAN_B;

    int pre = 0;
    for (int i = t; i < base; i += SCAN_B) pre += total[i];
    red[t] = pre;
    __syncthreads();
    for (int s = SCAN_B / 2; s > 0; s >>= 1) {
        if (t < s) red[t] += red[t + s];
        __syncthreads();
    }
    const int off0 = red[0];

    const int idx = base + t;
    const int v = (idx < N) ? total[idx] : 0;
    sdata[t] = v;
    __syncthreads();
    for (int off = 1; off < SCAN_B; off <<= 1) {
        int tmp = (t >= off) ? sdata[t - off] : 0;
        __syncthreads();
        sdata[t] += tmp;
        __syncthreads();
    }
    const int incl = sdata[t];
    if (idx < N) {
        rowstart[idx] = off0 + incl - v;
        dinv[idx] = rsqrtf(deg[idx]);    // deg >= 1 (self loop init)
    }
    if (idx == N - 1) rowstart[N] = off0 + incl;
}

// ---------------------------------------------------------------------------
// scatter edges into CSR slots — fully atomic-free:
//   pos = rowstart[dst] + chunkPre[chunk][dst] + rank[e],  chunk = e >> CH_LOG
// XCD-affine: block (blockIdx & 7)==k only writes edges whose dst falls in
// the k-th N/8-range (write locality in that XCD's L2).
// pk.x = byte offset of bf16 row (96B).
// ---------------------------------------------------------------------------
__global__ void fill_kernel(const int* __restrict__ src, const int* __restrict__ dst,
                            const float* __restrict__ ew, const float* __restrict__ dinv,
                            const int* __restrict__ rowstart,
                            const unsigned* __restrict__ chunkPre,
                            const int* __restrict__ rank,
                            int2* __restrict__ edges, int E, int R, int N)
{
    const int xcd   = blockIdx.x & 7;
    const int chunk = blockIdx.x >> 3;
    int e = chunk * 256 + threadIdx.x;
    if (e >= E) return;
    int d = dst[e];
    int lo = xcd * R;
    if (d < lo || d >= lo + R) return;
    int s = src[e];
    int c = e >> CH_LOG;
    int pos = rowstart[d] + (int)chunkPre[(size_t)c * N + d] + rank[e];
    int2 pk;
    pk.x = s * (FP * 2);                       // byte offset of bf16 x row
    pk.y = __float_as_int(dinv[s] * ew[e]);
    edges[pos] = pk;
}

// ---------------------------------------------------------------------------
// fused gather + node kernel (unchanged from R12): one wave per dst node.
// 5 edge slots x 12 lanes; bf16 rows as ushort4 (<<16 decode); cross-slot
// reduce via per-wave LDS; fp32 self-loop; LDS b128 broadcasts + rcp gates.
// ---------------------------------------------------------------------------
__global__ __launch_bounds__(256) void gather_node_kernel(
    const unsigned short* __restrict__ xs, const float* __restrict__ x,
    const int* __restrict__ rowstart,
    const int2* __restrict__ edges, const float* __restrict__ dinv,
    const float* __restrict__ probs,
    const float* __restrict__ Mz, const float* __restrict__ cz,
    const float* __restrict__ Mh, const float* __restrict__ ch,
    const float* __restrict__ Wc, const float* __restrict__ bc,
    float* __restrict__ out, int N)
{
    __shared__ __align__(16) float sWc[HID * FP];
    __shared__ __align__(16) float sprobs[16];
    __shared__ __align__(16) float yacc[4][240];
    __shared__ __align__(16) float yld[4][FP];
    __shared__ __align__(16) float hld[4][HID];
    for (int i = threadIdx.x; i < HID * FP; i += 256) sWc[i] = Wc[i];
    if (threadIdx.x < NP) sprobs[threadIdx.x] = probs[threadIdx.x];
    __syncthreads();

    const int lane = threadIdx.x & 63;
    const int wib  = threadIdx.x >> 6;
    const int n    = blockIdx.x * 4 + wib;
    if (n >= N) return;

    const int slot = lane / 12;
    const int q    = lane - slot * 12;
    const bool act = (slot < 5);
    const char* xsb = (const char*)xs;

    const int beg = rowstart[n];
    const int end = rowstart[n + 1];

    float4 acc = make_float4(0.f, 0.f, 0.f, 0.f);
    {
        int e = beg + slot;
        int2 pk = edges[e];                           // padded: always safe
        float w  = (act && e < end) ? __int_as_float(pk.y) : 0.f;
        int  off = pk.x;
        #pragma unroll 4
        for (int e0 = beg; e0 < end; e0 += 5) {
            const float wc  = w;
            const int   ofc = off;
            e += 5;
            int2 pk2 = edges[e];                      // prefetch next (padded)
            w   = (act && e < end) ? __int_as_float(pk2.y) : 0.f;
            off = pk2.x;
            const ushort4 xv = *reinterpret_cast<const ushort4*>(xsb + ofc + (q << 3));
            acc.x += wc * __uint_as_float((unsigned)xv.x << 16);
            acc.y += wc * __uint_as_float((unsigned)xv.y << 16);
            acc.z += wc * __uint_as_float((unsigned)xv.z << 16);
            acc.w += wc * __uint_as_float((unsigned)xv.w << 16);
        }
    }

    if (act)
        *reinterpret_cast<float4*>(&yacc[wib][slot * 48 + q * 4]) = acc;

    const float di = dinv[n];
    if (lane < FP) {
        const float* yf = yacc[wib];
        float s = yf[lane] + yf[48 + lane] + yf[96 + lane] + yf[144 + lane] + yf[192 + lane];
        float xself = x[(size_t)n * FP + lane];      // fp32 self-loop (exact)
        float yv = di * s + di * di * xself;
        int f = lane / 12;
        int p = lane - f * 12;
        yld[wib][p * 4 + f] = yv;
    }

    const float mz0 = Mz[lane], mz1 = Mz[64 + lane], mz2 = Mz[128 + lane], mz3 = Mz[192 + lane];
    const float mh0 = Mh[lane], mh1 = Mh[64 + lane], mh2 = Mh[128 + lane], mh3 = Mh[192 + lane];
    const float czv = cz[lane], chv = ch[lane];
    const int   c   = (lane < FP) ? lane : 0;
    const float bcv = bc[c];

    const float* yw = yld[wib];
    float hacc = 0.f;
    #pragma unroll
    for (int p = 0; p < NP; ++p) {
        const float4 v = *reinterpret_cast<const float4*>(yw + p * 4);
        float az = czv + v.x * mz0 + v.y * mz1 + v.z * mz2 + v.w * mz3;
        float ah = chv + v.x * mh0 + v.y * mh1 + v.z * mh2 + v.w * mh3;
        float g  = __builtin_amdgcn_rcpf(1.f + __expf(az));
        float ahc = fminf(fmaxf(ah, -15.f), 15.f);
        float eh = __expf(2.f * ahc);
        float th = 1.f - 2.f * __builtin_amdgcn_rcpf(eh + 1.f);
        hacc += sprobs[p] * g * th;
    }
    hacc = fmaxf(hacc, 0.f);

    hld[wib][lane] = hacc;
    const float* hw = hld[wib];
    float o = bcv;
    #pragma unroll
    for (int i4 = 0; i4 < 16; ++i4) {
        const float4 h4 = *reinterpret_cast<const float4*>(hw + i4 * 4);
        o += h4.x * sWc[(i4 * 4 + 0) * FP + c];
        o += h4.y * sWc[(i4 * 4 + 1) * FP + c];
        o += h4.z * sWc[(i4 * 4 + 2) * FP + c];
        o += h4.w * sWc[(i4 * 4 + 3) * FP + c];
    }
    if (lane < FP) out[(size_t)n * FP + lane] = o;
}

// ---------------------------------------------------------------------------
extern "C" void kernel_launch(void* const* d_in, const int* in_sizes, int n_in,
                              void* d_out, int out_size, void* d_ws, size_t ws_size,
                              hipStream_t stream)
{
    const int N = in_sizes[0] / FP;   // 50000
    const int E = in_sizes[1] / 2;    // 1.6M
    const int NB = (N + SCAN_B - 1) / SCAN_B;
    const int nchunks = (E + CH - 1) >> CH_LOG;   // ~98

    const float* x    = (const float*)d_in[0];
    const int*   ei   = (const int*)d_in[1];
    const float* ew   = (const float*)d_in[2];
    const float* att  = (const float*)d_in[3];
    const float* Wg_z = (const float*)d_in[4];
    const float* bg_z = (const float*)d_in[5];
    const float* Wl_z = (const float*)d_in[6];
    const float* bl_z = (const float*)d_in[7];
    // d_in[8..11] = r-gate params: unused (H=0 => Hz*r = 0)
    const float* Wg_h = (const float*)d_in[12];
    const float* bg_h = (const float*)d_in[13];
    const float* Wl_h = (const float*)d_in[14];
    const float* bl_h = (const float*)d_in[15];
    const float* W1 = (const float*)d_in[16]; const float* b1 = (const float*)d_in[17];
    const float* W2 = (const float*)d_in[18]; const float* b2 = (const float*)d_in[19];
    const float* W3 = (const float*)d_in[20]; const float* b3 = (const float*)d_in[21];
    const float* W4 = (const float*)d_in[22]; const float* b4 = (const float*)d_in[23];
    const float* Wo = (const float*)d_in[24]; const float* bo = (const float*)d_in[25];

    const int* srcp = ei;
    const int* dstp = ei + E;

    // workspace layout (8B-aligned items first) — ~55 MB of 256 MiB ws
    int2*  edges     = (int2*)d_ws;                                      // E + 16 (pad)
    unsigned short* xs = (unsigned short*)(edges + E + 16);              // N*FP bf16
    float* deg       = (float*)(xs + (size_t)N * FP);                    // N
    int*   rank      = (int*)(deg + N);                                  // E
    float* dinv      = (float*)(rank + E);                               // N
    int*   rowstart  = (int*)(dinv + N);                                 // N+1
    int*   total     = rowstart + N + 1;                                 // N
    unsigned* chunkCnt = (unsigned*)(total + N + 63);                    // nchunks*NW
    unsigned* chunkPre = chunkCnt + (size_t)nchunks * NW;                // nchunks*N
    float* probs     = (float*)(chunkPre + (size_t)nchunks * N + 63);    // 16
    float* Mz        = probs + 16;                                       // 256
    float* cz        = Mz + 256;                                         // 64
    float* Mh        = cz + 64;                                          // 256
    float* ch        = Mh + 256;                                         // 64
    float* Wc        = ch + 64;                                          // 3072
    float* bc        = Wc + HID * FP;                                    // 48

    const int initBlocks = (N + 255) / 256;
    init_prep_kernel<<<initBlocks + 1, 256, 0, stream>>>(
        att, Wg_z, bg_z, Wl_z, bl_z, Wg_h, bg_h, Wl_h, bl_h,
        W1, b1, W2, b2, W3, b3, W4, b4, Wo, bo,
        probs, Mz, cz, Mh, ch, Wc, bc,
        deg, edges + E, x, xs, N, initBlocks);

    hist_kernel<<<nchunks, 1024, 0, stream>>>(dstp, ew, deg, chunkCnt, rank, E);
    chunkpre_kernel<<<(N + 1023) / 1024, 1024, 0, stream>>>(chunkCnt, chunkPre, total, N, nchunks);
    scan_kernel<<<NB, SCAN_B, 0, stream>>>(total, deg, rowstart, dinv, N);

    const int R = (N + 7) / 8;                          // dst-range per XCD bin
    const int chunks256 = (E + 255) / 256;
    fill_kernel<<<chunks256 * 8, 256, 0, stream>>>(srcp, dstp, ew, dinv, rowstart,
                                                   chunkPre, rank, edges, E, R, N);

    gather_node_kernel<<<(N + 3) / 4, 256, 0, stream>>>(xs, x, rowstart, edges, dinv,
                                                        probs, Mz, cz, Mh, ch, Wc, bc,
                                                        (float*)d_out, N);
}

// Round 14
// 327.333 us; speedup vs baseline: 1.2114x; 1.2114x over previous
//
#include <hip/hip_runtime.h>
#include <hip/hip_bf16.h>

// Problem constants (shapes fixed by reference)
#define FP 48   // F*P = 4*12 floats per node
#define HID 64
#define NP 12   // periods
#define NF 4    // input feats
#define SCAN_B 1024
#define PL 65   // padded LDS stride for prep tiles

// ---------------------------------------------------------------------------
// prep helpers: register-tiled 64x64 @ 64x64 (A in LDS stride-65, B global)
// ---------------------------------------------------------------------------
__device__ __forceinline__ void mm_stage(const float* __restrict__ Alds,
                                         const float* __restrict__ Wg,
                                         float* __restrict__ Clds, int t)
{
    const int rg = (t >> 4) * 4, cg = (t & 15) * 4;
    float acc[4][4] = {};
    for (int k = 0; k < 64; ++k) {
        float a0 = Alds[(rg + 0) * PL + k];
        float a1 = Alds[(rg + 1) * PL + k];
        float a2 = Alds[(rg + 2) * PL + k];
        float a3 = Alds[(rg + 3) * PL + k];
        const float4 bv = *reinterpret_cast<const float4*>(Wg + k * 64 + cg);
        acc[0][0] += a0 * bv.x; acc[0][1] += a0 * bv.y; acc[0][2] += a0 * bv.z; acc[0][3] += a0 * bv.w;
        acc[1][0] += a1 * bv.x; acc[1][1] += a1 * bv.y; acc[1][2] += a1 * bv.z; acc[1][3] += a1 * bv.w;
        acc[2][0] += a2 * bv.x; acc[2][1] += a2 * bv.y; acc[2][2] += a2 * bv.z; acc[2][3] += a2 * bv.w;
        acc[3][0] += a3 * bv.x; acc[3][1] += a3 * bv.y; acc[3][2] += a3 * bv.z; acc[3][3] += a3 * bv.w;
    }
    for (int i = 0; i < 4; ++i)
        for (int j = 0; j < 4; ++j)
            Clds[(rg + i) * PL + cg + j] = acc[i][j];
}

__device__ __forceinline__ void bias_stage(const float* __restrict__ bin,
                                           const float* __restrict__ Wg,
                                           const float* __restrict__ badd,
                                           float* __restrict__ bout, int t)
{
    if (t < 64) {
        float s = badd[t];
        for (int k = 0; k < 64; ++k) s += bin[k] * Wg[k * 64 + t];
        bout[t] = s;
    }
}

// bf16 round-to-nearest-even (x ~ N(0,1): no inf/nan concerns)
__device__ __forceinline__ unsigned short f2bf(float v)
{
    unsigned u = __float_as_uint(v);
    return (unsigned short)((u + 0x7fffu + ((u >> 16) & 1u)) >> 16);
}

// ---------------------------------------------------------------------------
// fused init + prep: block 0 does the weight-collapse prep; blocks >=1 zero
// the packed histogram + edge pad AND convert x (fp32) -> xs (bf16 rows,
// 96B/row) so the gather's working set (4.8MB) becomes L2-resident.
// r-gate params provably unused (H=0 => Hz*r = 0).
// ---------------------------------------------------------------------------
__global__ __launch_bounds__(256) void init_prep_kernel(
    const float* __restrict__ att,
    const float* __restrict__ Wg_z, const float* __restrict__ bg_z,
    const float* __restrict__ Wl_z, const float* __restrict__ bl_z,
    const float* __restrict__ Wg_h, const float* __restrict__ bg_h,
    const float* __restrict__ Wl_h, const float* __restrict__ bl_h,
    const float* __restrict__ W1, const float* __restrict__ b1,
    const float* __restrict__ W2, const float* __restrict__ b2,
    const float* __restrict__ W3, const float* __restrict__ b3,
    const float* __restrict__ W4, const float* __restrict__ b4,
    const float* __restrict__ Wo, const float* __restrict__ bo,
    float* __restrict__ probs, float* __restrict__ Mz, float* __restrict__ cz,
    float* __restrict__ Mh, float* __restrict__ ch,
    float* __restrict__ Wc, float* __restrict__ bc,
    unsigned* __restrict__ packed, int2* __restrict__ edgepad,
    const float* __restrict__ x, unsigned short* __restrict__ xs,
    int N, int nblk)
{
    const int t = threadIdx.x;

    if (blockIdx.x > 0) {
        int i = (blockIdx.x - 1) * 256 + t;
        if (i < N) packed[i] = 0u;
        if (blockIdx.x == 1 && t < 16) edgepad[t] = make_int2(0, 0);
        // x -> bf16 conversion, float4-stride over N*FP/4 quads
        const int nq = N * (FP / 4);
        const int stride = nblk * 256;
        for (int j = (blockIdx.x - 1) * 256 + t; j < nq; j += stride) {
            const float4 v = *reinterpret_cast<const float4*>(x + j * 4);
            ushort4 o;
            o.x = f2bf(v.x); o.y = f2bf(v.y); o.z = f2bf(v.z); o.w = f2bf(v.w);
            *reinterpret_cast<ushort4*>(xs + j * 4) = o;
        }
        return;
    }

    __shared__ float A[64 * PL];
    __shared__ float B[64 * PL];
    __shared__ float bias[64];
    __shared__ float bias2[64];

    if (t == 0) {
        float m = att[0];
        for (int p = 1; p < NP; ++p) m = fmaxf(m, att[p]);
        float e[NP]; float s = 0.f;
        for (int p = 0; p < NP; ++p) { e[p] = __expf(att[p] - m); s += e[p]; }
        float inv = 1.f / s;
        for (int p = 0; p < NP; ++p) probs[p] = e[p] * inv;
    }

    // gate matrices: Mz/Mh 4x64; thread t -> (f=t>>6, j=t&63)
    {
        int f = t >> 6, j = t & 63;
        float az = 0.f, ah = 0.f;
        for (int k = 0; k < HID; ++k) {
            az += Wg_z[f * HID + k] * Wl_z[k * HID + j];
            ah += Wg_h[f * HID + k] * Wl_h[k * HID + j];
        }
        Mz[t] = az; Mh[t] = ah;
    }
    if (t < HID) {
        float az = bl_z[t], ah = bl_h[t];
        for (int k = 0; k < HID; ++k) {
            az += bg_z[k] * Wl_z[k * HID + t];
            ah += bg_h[k] * Wl_h[k * HID + t];
        }
        cz[t] = az; ch[t] = ah;
    }

    // load W1 -> A (padded)
    for (int idx = t; idx < 4096; idx += 256) {
        int i = idx >> 6, j = idx & 63;
        A[i * PL + j] = W1[idx];
    }
    if (t < 64) bias[t] = b1[t];
    __syncthreads();

    mm_stage(A, W2, B, t);                 // B = W1@W2
    bias_stage(bias, W2, b2, bias2, t);    // bias2 = b1@W2 + b2
    __syncthreads();
    mm_stage(B, W3, A, t);                 // A = (W1W2)@W3
    bias_stage(bias2, W3, b3, bias, t);
    __syncthreads();
    mm_stage(A, W4, B, t);                 // B = (W1W2W3)@W4
    bias_stage(bias, W4, b4, bias2, t);
    __syncthreads();

    // final: Wc = B @ Wo (64x48), bc = bias2@Wo + bo
    {
        const int rg = (t >> 4) * 4, cg = (t & 15) * 4;
        if (cg < FP) {
            float acc[4][4] = {};
            for (int k = 0; k < 64; ++k) {
                float a0 = B[(rg + 0) * PL + k];
                float a1 = B[(rg + 1) * PL + k];
                float a2 = B[(rg + 2) * PL + k];
                float a3 = B[(rg + 3) * PL + k];
                const float4 bv = *reinterpret_cast<const float4*>(Wo + k * FP + cg);
                acc[0][0] += a0 * bv.x; acc[0][1] += a0 * bv.y; acc[0][2] += a0 * bv.z; acc[0][3] += a0 * bv.w;
                acc[1][0] += a1 * bv.x; acc[1][1] += a1 * bv.y; acc[1][2] += a1 * bv.z; acc[1][3] += a1 * bv.w;
                acc[2][0] += a2 * bv.x; acc[2][1] += a2 * bv.y; acc[2][2] += a2 * bv.z; acc[2][3] += a2 * bv.w;
                acc[3][0] += a3 * bv.x; acc[3][1] += a3 * bv.y; acc[3][2] += a3 * bv.z; acc[3][3] += a3 * bv.w;
            }
            for (int i = 0; i < 4; ++i)
                for (int j = 0; j < 4; ++j)
                    Wc[(rg + i) * FP + cg + j] = acc[i][j];
        }
        if (t < FP) {
            float s = bo[t];
            for (int k = 0; k < 64; ++k) s += bias2[k] * Wo[k * FP + t];
            bc[t] = s;
        }
    }
}

// ---------------------------------------------------------------------------
// CSR construction. packed[n] (u32) = (count << 24) | fixedpoint16(sum ew).
// Atomic return yields this edge's per-dst rank (stored coalesced) so fill
// needs NO atomic. Bit budget: in-degree << 255; sum ew < 256 so sum*2^16 <
// 2^24 — fields never collide. hist is bound by returned-atomic throughput
// (~19.5G/s measured R10-R12; LDS-chunked alternative regressed in R13 due
// to 100KB-LDS occupancy collapse — revert decision, see journal).
// ---------------------------------------------------------------------------
__global__ void hist_kernel(const int* __restrict__ dst, const float* __restrict__ ew,
                            unsigned* __restrict__ packed,
                            int* __restrict__ rank, int E)
{
    int e = blockIdx.x * blockDim.x + threadIdx.x;
    if (e < E) {
        int d = dst[e];
        unsigned v = (1u << 24) | (unsigned)__float2uint_rn(ew[e] * 65536.f);
        unsigned old = atomicAdd(&packed[d], v);
        rank[e] = (int)(old >> 24);
    }
}

// ---------------------------------------------------------------------------
// fused scan: block b sums counts of all indices < b*1024 (coalesced), then
// local Hillis-Steele scan. Also computes dinv = rsqrt(1 + sum ew).
// ---------------------------------------------------------------------------
__global__ __launch_bounds__(SCAN_B) void scan_kernel(const unsigned* __restrict__ packed,
                                                      int* __restrict__ rowstart,
                                                      float* __restrict__ dinv, int N)
{
    __shared__ int red[SCAN_B];
    __shared__ int sdata[SCAN_B];
    const int t = threadIdx.x;
    const int base = blockIdx.x * SCAN_B;

    int pre = 0;
    for (int i = t; i < base; i += SCAN_B) pre += (int)(packed[i] >> 24);
    red[t] = pre;
    __syncthreads();
    for (int s = SCAN_B / 2; s > 0; s >>= 1) {
        if (t < s) red[t] += red[t + s];
        __syncthreads();
    }
    const int off0 = red[0];

    const int idx = base + t;
    const unsigned pk = (idx < N) ? packed[idx] : 0u;
    const int v = (int)(pk >> 24);
    sdata[t] = v;
    __syncthreads();
    for (int off = 1; off < SCAN_B; off <<= 1) {
        int tmp = (t >= off) ? sdata[t - off] : 0;
        __syncthreads();
        sdata[t] += tmp;
        __syncthreads();
    }
    const int incl = sdata[t];
    if (idx < N) {
        rowstart[idx] = off0 + incl - v;
        float deg = 1.0f + (float)(pk & 0xFFFFFFu) * (1.0f / 65536.0f);
        dinv[idx] = rsqrtf(deg);   // deg >= 1 always (self loop)
    }
    if (idx == N - 1) rowstart[N] = off0 + incl;
}

// ---------------------------------------------------------------------------
// scatter edges into CSR slots — atomic-free: pos = rowstart[dst] + rank[e].
// SINGLE dispatch (A/B vs the R9-R12 8x XCD-affine split, which cost 8x dst
// reads + 44k near-empty blocks and whose L2-merge benefit was never
// isolated). pk.x = byte offset of bf16 row (96B).
// ---------------------------------------------------------------------------
__global__ void fill_kernel(const int* __restrict__ src, const int* __restrict__ dst,
                            const float* __restrict__ ew, const float* __restrict__ dinv,
                            const int* __restrict__ rowstart, const int* __restrict__ rank,
                            int2* __restrict__ edges, int E)
{
    int e = blockIdx.x * blockDim.x + threadIdx.x;
    if (e >= E) return;
    int d = dst[e];
    int s = src[e];
    int pos = rowstart[d] + rank[e];
    int2 pk;
    pk.x = s * (FP * 2);                       // byte offset of bf16 x row
    pk.y = __float_as_int(dinv[s] * ew[e]);
    edges[pos] = pk;
}

// ---------------------------------------------------------------------------
// fused gather + node kernel (unchanged from R12): one wave per dst node.
// 5 edge slots x 12 lanes; bf16 rows as ushort4 (<<16 decode); cross-slot
// reduce via per-wave LDS; fp32 self-loop; LDS b128 broadcasts + rcp gates.
// ---------------------------------------------------------------------------
__global__ __launch_bounds__(256) void gather_node_kernel(
    const unsigned short* __restrict__ xs, const float* __restrict__ x,
    const int* __restrict__ rowstart,
    const int2* __restrict__ edges, const float* __restrict__ dinv,
    const float* __restrict__ probs,
    const float* __restrict__ Mz, const float* __restrict__ cz,
    const float* __restrict__ Mh, const float* __restrict__ ch,
    const float* __restrict__ Wc, const float* __restrict__ bc,
    float* __restrict__ out, int N)
{
    __shared__ __align__(16) float sWc[HID * FP];
    __shared__ __align__(16) float sprobs[16];
    __shared__ __align__(16) float yacc[4][240];
    __shared__ __align__(16) float yld[4][FP];
    __shared__ __align__(16) float hld[4][HID];
    for (int i = threadIdx.x; i < HID * FP; i += 256) sWc[i] = Wc[i];
    if (threadIdx.x < NP) sprobs[threadIdx.x] = probs[threadIdx.x];
    __syncthreads();

    const int lane = threadIdx.x & 63;
    const int wib  = threadIdx.x >> 6;
    const int n    = blockIdx.x * 4 + wib;
    if (n >= N) return;

    const int slot = lane / 12;            // 0..4 active, 5 = idle lanes 60..63
    const int q    = lane - slot * 12;     // ushort4 index within row, 0..11
    const bool act = (slot < 5);
    const char* xsb = (const char*)xs;

    const int beg = rowstart[n];
    const int end = rowstart[n + 1];

    float4 acc = make_float4(0.f, 0.f, 0.f, 0.f);
    {
        int e = beg + slot;
        int2 pk = edges[e];                           // padded: always safe
        float w  = (act && e < end) ? __int_as_float(pk.y) : 0.f;
        int  off = pk.x;
        #pragma unroll 4
        for (int e0 = beg; e0 < end; e0 += 5) {
            const float wc  = w;
            const int   ofc = off;
            e += 5;
            int2 pk2 = edges[e];                      // prefetch next (padded)
            w   = (act && e < end) ? __int_as_float(pk2.y) : 0.f;
            off = pk2.x;
            const ushort4 xv = *reinterpret_cast<const ushort4*>(xsb + ofc + (q << 3));
            acc.x += wc * __uint_as_float((unsigned)xv.x << 16);
            acc.y += wc * __uint_as_float((unsigned)xv.y << 16);
            acc.z += wc * __uint_as_float((unsigned)xv.z << 16);
            acc.w += wc * __uint_as_float((unsigned)xv.w << 16);
        }
    }

    if (act)
        *reinterpret_cast<float4*>(&yacc[wib][slot * 48 + q * 4]) = acc;

    const float di = dinv[n];
    if (lane < FP) {
        const float* yf = yacc[wib];
        float s = yf[lane] + yf[48 + lane] + yf[96 + lane] + yf[144 + lane] + yf[192 + lane];
        float xself = x[(size_t)n * FP + lane];      // fp32 self-loop (exact)
        float yv = di * s + di * di * xself;
        int f = lane / 12;
        int p = lane - f * 12;
        yld[wib][p * 4 + f] = yv;
    }

    const float mz0 = Mz[lane], mz1 = Mz[64 + lane], mz2 = Mz[128 + lane], mz3 = Mz[192 + lane];
    const float mh0 = Mh[lane], mh1 = Mh[64 + lane], mh2 = Mh[128 + lane], mh3 = Mh[192 + lane];
    const float czv = cz[lane], chv = ch[lane];
    const int   c   = (lane < FP) ? lane : 0;
    const float bcv = bc[c];

    const float* yw = yld[wib];
    float hacc = 0.f;
    #pragma unroll
    for (int p = 0; p < NP; ++p) {
        const float4 v = *reinterpret_cast<const float4*>(yw + p * 4);
        float az = czv + v.x * mz0 + v.y * mz1 + v.z * mz2 + v.w * mz3;
        float ah = chv + v.x * mh0 + v.y * mh1 + v.z * mh2 + v.w * mh3;
        float g  = __builtin_amdgcn_rcpf(1.f + __expf(az));
        float ahc = fminf(fmaxf(ah, -15.f), 15.f);
        float eh = __expf(2.f * ahc);
        float th = 1.f - 2.f * __builtin_amdgcn_rcpf(eh + 1.f);
        hacc += sprobs[p] * g * th;
    }
    hacc = fmaxf(hacc, 0.f);

    hld[wib][lane] = hacc;
    const float* hw = hld[wib];
    float o = bcv;
    #pragma unroll
    for (int i4 = 0; i4 < 16; ++i4) {
        const float4 h4 = *reinterpret_cast<const float4*>(hw + i4 * 4);
        o += h4.x * sWc[(i4 * 4 + 0) * FP + c];
        o += h4.y * sWc[(i4 * 4 + 1) * FP + c];
        o += h4.z * sWc[(i4 * 4 + 2) * FP + c];
        o += h4.w * sWc[(i4 * 4 + 3) * FP + c];
    }
    if (lane < FP) out[(size_t)n * FP + lane] = o;
}

// ---------------------------------------------------------------------------
extern "C" void kernel_launch(void* const* d_in, const int* in_sizes, int n_in,
                              void* d_out, int out_size, void* d_ws, size_t ws_size,
                              hipStream_t stream)
{
    const int N = in_sizes[0] / FP;   // 50000
    const int E = in_sizes[1] / 2;    // 1.6M
    const int NB = (N + SCAN_B - 1) / SCAN_B;

    const float* x    = (const float*)d_in[0];
    const int*   ei   = (const int*)d_in[1];
    const float* ew   = (const float*)d_in[2];
    const float* att  = (const float*)d_in[3];
    const float* Wg_z = (const float*)d_in[4];
    const float* bg_z = (const float*)d_in[5];
    const float* Wl_z = (const float*)d_in[6];
    const float* bl_z = (const float*)d_in[7];
    // d_in[8..11] = r-gate params: unused (H=0 => Hz*r = 0)
    const float* Wg_h = (const float*)d_in[12];
    const float* bg_h = (const float*)d_in[13];
    const float* Wl_h = (const float*)d_in[14];
    const float* bl_h = (const float*)d_in[15];
    const float* W1 = (const float*)d_in[16]; const float* b1 = (const float*)d_in[17];
    const float* W2 = (const float*)d_in[18]; const float* b2 = (const float*)d_in[19];
    const float* W3 = (const float*)d_in[20]; const float* b3 = (const float*)d_in[21];
    const float* W4 = (const float*)d_in[22]; const float* b4 = (const float*)d_in[23];
    const float* Wo = (const float*)d_in[24]; const float* bo = (const float*)d_in[25];

    const int* srcp = ei;
    const int* dstp = ei + E;

    // workspace layout (8B-aligned items first) — ~25 MB of 256 MiB ws
    int2*  edges    = (int2*)d_ws;                                       // E + 16 (pad)
    unsigned short* xs = (unsigned short*)(edges + E + 16);              // N*FP bf16
    unsigned* packed= (unsigned*)(xs + (size_t)N * FP);                  // N (u32)
    int*   rank     = (int*)(packed + N);                                // E
    float* dinv     = (float*)(rank + E);                                // N
    int*   rowstart = (int*)(dinv + N);                                  // N+1
    float* probs    = (float*)(rowstart + N + 1 + 63);                   // 16 (padded)
    float* Mz       = probs + 16;                                        // 256
    float* cz       = Mz + 256;                                          // 64
    float* Mh       = cz + 64;                                           // 256
    float* ch       = Mh + 256;                                          // 64
    float* Wc       = ch + 64;                                           // 3072
    float* bc       = Wc + HID * FP;                                     // 48

    const int initBlocks = (N + 255) / 256;
    init_prep_kernel<<<initBlocks + 1, 256, 0, stream>>>(
        att, Wg_z, bg_z, Wl_z, bl_z, Wg_h, bg_h, Wl_h, bl_h,
        W1, b1, W2, b2, W3, b3, W4, b4, Wo, bo,
        probs, Mz, cz, Mh, ch, Wc, bc,
        packed, edges + E, x, xs, N, initBlocks);

    hist_kernel<<<(E + 255) / 256, 256, 0, stream>>>(dstp, ew, packed, rank, E);
    scan_kernel<<<NB, SCAN_B, 0, stream>>>(packed, rowstart, dinv, N);
    fill_kernel<<<(E + 255) / 256, 256, 0, stream>>>(srcp, dstp, ew, dinv, rowstart, rank, edges, E);

    gather_node_kernel<<<(N + 3) / 4, 256, 0, stream>>>(xs, x, rowstart, edges, dinv,
                                                        probs, Mz, cz, Mh, ch, Wc, bc,
                                                        (float*)d_out, N);
}

// Round 15
// 324.152 us; speedup vs baseline: 1.2233x; 1.0098x over previous
//
#include <hip/hip_runtime.h>
#include <hip/hip_bf16.h>

// Problem constants (shapes fixed by reference)
#define FP 48   // F*P = 4*12 floats per node
#define HID 64
#define NP 12   // periods
#define NF 4    // input feats
#define SCAN_B 1024
#define PL 65   // padded LDS stride for prep tiles

// ---------------------------------------------------------------------------
// prep helpers: register-tiled 64x64 @ 64x64 (A in LDS stride-65, B global)
// ---------------------------------------------------------------------------
__device__ __forceinline__ void mm_stage(const float* __restrict__ Alds,
                                         const float* __restrict__ Wg,
                                         float* __restrict__ Clds, int t)
{
    const int rg = (t >> 4) * 4, cg = (t & 15) * 4;
    float acc[4][4] = {};
    for (int k = 0; k < 64; ++k) {
        float a0 = Alds[(rg + 0) * PL + k];
        float a1 = Alds[(rg + 1) * PL + k];
        float a2 = Alds[(rg + 2) * PL + k];
        float a3 = Alds[(rg + 3) * PL + k];
        const float4 bv = *reinterpret_cast<const float4*>(Wg + k * 64 + cg);
        acc[0][0] += a0 * bv.x; acc[0][1] += a0 * bv.y; acc[0][2] += a0 * bv.z; acc[0][3] += a0 * bv.w;
        acc[1][0] += a1 * bv.x; acc[1][1] += a1 * bv.y; acc[1][2] += a1 * bv.z; acc[1][3] += a1 * bv.w;
        acc[2][0] += a2 * bv.x; acc[2][1] += a2 * bv.y; acc[2][2] += a2 * bv.z; acc[2][3] += a2 * bv.w;
        acc[3][0] += a3 * bv.x; acc[3][1] += a3 * bv.y; acc[3][2] += a3 * bv.z; acc[3][3] += a3 * bv.w;
    }
    for (int i = 0; i < 4; ++i)
        for (int j = 0; j < 4; ++j)
            Clds[(rg + i) * PL + cg + j] = acc[i][j];
}

__device__ __forceinline__ void bias_stage(const float* __restrict__ bin,
                                           const float* __restrict__ Wg,
                                           const float* __restrict__ badd,
                                           float* __restrict__ bout, int t)
{
    if (t < 64) {
        float s = badd[t];
        for (int k = 0; k < 64; ++k) s += bin[k] * Wg[k * 64 + t];
        bout[t] = s;
    }
}

// bf16 round-to-nearest-even (x ~ N(0,1): no inf/nan concerns)
__device__ __forceinline__ unsigned short f2bf(float v)
{
    unsigned u = __float_as_uint(v);
    return (unsigned short)((u + 0x7fffu + ((u >> 16) & 1u)) >> 16);
}

// ---------------------------------------------------------------------------
// fused init + prep: block 0 does the weight-collapse prep; blocks >=1 zero
// the packed histogram AND the padded edges array (pad slots must read as
// w=0) AND convert x (fp32) -> xs (bf16 rows, 96B/row; 4.8MB L2-resident).
// r-gate params provably unused (H=0 => Hz*r = 0).
// ---------------------------------------------------------------------------
__global__ __launch_bounds__(256) void init_prep_kernel(
    const float* __restrict__ att,
    const float* __restrict__ Wg_z, const float* __restrict__ bg_z,
    const float* __restrict__ Wl_z, const float* __restrict__ bl_z,
    const float* __restrict__ Wg_h, const float* __restrict__ bg_h,
    const float* __restrict__ Wl_h, const float* __restrict__ bl_h,
    const float* __restrict__ W1, const float* __restrict__ b1,
    const float* __restrict__ W2, const float* __restrict__ b2,
    const float* __restrict__ W3, const float* __restrict__ b3,
    const float* __restrict__ W4, const float* __restrict__ b4,
    const float* __restrict__ Wo, const float* __restrict__ bo,
    float* __restrict__ probs, float* __restrict__ Mz, float* __restrict__ cz,
    float* __restrict__ Mh, float* __restrict__ ch,
    float* __restrict__ Wc, float* __restrict__ bc,
    unsigned* __restrict__ packed, int2* __restrict__ edges, int Epad,
    const float* __restrict__ x, unsigned short* __restrict__ xs,
    int N, int nblk)
{
    const int t = threadIdx.x;

    if (blockIdx.x > 0) {
        int i = (blockIdx.x - 1) * 256 + t;
        if (i < N) packed[i] = 0u;
        const int stride = nblk * 256;
        // zero padded edges array (pad slots -> {off=0, w=0})
        for (int j = (blockIdx.x - 1) * 256 + t; j < Epad; j += stride)
            edges[j] = make_int2(0, 0);
        // x -> bf16 conversion, float4-stride over N*FP/4 quads
        const int nq = N * (FP / 4);
        for (int j = (blockIdx.x - 1) * 256 + t; j < nq; j += stride) {
            const float4 v = *reinterpret_cast<const float4*>(x + j * 4);
            ushort4 o;
            o.x = f2bf(v.x); o.y = f2bf(v.y); o.z = f2bf(v.z); o.w = f2bf(v.w);
            *reinterpret_cast<ushort4*>(xs + j * 4) = o;
        }
        return;
    }

    __shared__ float A[64 * PL];
    __shared__ float B[64 * PL];
    __shared__ float bias[64];
    __shared__ float bias2[64];

    if (t == 0) {
        float m = att[0];
        for (int p = 1; p < NP; ++p) m = fmaxf(m, att[p]);
        float e[NP]; float s = 0.f;
        for (int p = 0; p < NP; ++p) { e[p] = __expf(att[p] - m); s += e[p]; }
        float inv = 1.f / s;
        for (int p = 0; p < NP; ++p) probs[p] = e[p] * inv;
    }

    // gate matrices: Mz/Mh 4x64; thread t -> (f=t>>6, j=t&63)
    {
        int f = t >> 6, j = t & 63;
        float az = 0.f, ah = 0.f;
        for (int k = 0; k < HID; ++k) {
            az += Wg_z[f * HID + k] * Wl_z[k * HID + j];
            ah += Wg_h[f * HID + k] * Wl_h[k * HID + j];
        }
        Mz[t] = az; Mh[t] = ah;
    }
    if (t < HID) {
        float az = bl_z[t], ah = bl_h[t];
        for (int k = 0; k < HID; ++k) {
            az += bg_z[k] * Wl_z[k * HID + t];
            ah += bg_h[k] * Wl_h[k * HID + t];
        }
        cz[t] = az; ch[t] = ah;
    }

    // load W1 -> A (padded)
    for (int idx = t; idx < 4096; idx += 256) {
        int i = idx >> 6, j = idx & 63;
        A[i * PL + j] = W1[idx];
    }
    if (t < 64) bias[t] = b1[t];
    __syncthreads();

    mm_stage(A, W2, B, t);                 // B = W1@W2
    bias_stage(bias, W2, b2, bias2, t);    // bias2 = b1@W2 + b2
    __syncthreads();
    mm_stage(B, W3, A, t);                 // A = (W1W2)@W3
    bias_stage(bias2, W3, b3, bias, t);
    __syncthreads();
    mm_stage(A, W4, B, t);                 // B = (W1W2W3)@W4
    bias_stage(bias, W4, b4, bias2, t);
    __syncthreads();

    // final: Wc = B @ Wo (64x48), bc = bias2@Wo + bo
    {
        const int rg = (t >> 4) * 4, cg = (t & 15) * 4;
        if (cg < FP) {
            float acc[4][4] = {};
            for (int k = 0; k < 64; ++k) {
                float a0 = B[(rg + 0) * PL + k];
                float a1 = B[(rg + 1) * PL + k];
                float a2 = B[(rg + 2) * PL + k];
                float a3 = B[(rg + 3) * PL + k];
                const float4 bv = *reinterpret_cast<const float4*>(Wo + k * FP + cg);
                acc[0][0] += a0 * bv.x; acc[0][1] += a0 * bv.y; acc[0][2] += a0 * bv.z; acc[0][3] += a0 * bv.w;
                acc[1][0] += a1 * bv.x; acc[1][1] += a1 * bv.y; acc[1][2] += a1 * bv.z; acc[1][3] += a1 * bv.w;
                acc[2][0] += a2 * bv.x; acc[2][1] += a2 * bv.y; acc[2][2] += a2 * bv.z; acc[2][3] += a2 * bv.w;
                acc[3][0] += a3 * bv.x; acc[3][1] += a3 * bv.y; acc[3][2] += a3 * bv.z; acc[3][3] += a3 * bv.w;
            }
            for (int i = 0; i < 4; ++i)
                for (int j = 0; j < 4; ++j)
                    Wc[(rg + i) * FP + cg + j] = acc[i][j];
        }
        if (t < FP) {
            float s = bo[t];
            for (int k = 0; k < 64; ++k) s += bias2[k] * Wo[k * FP + t];
            bc[t] = s;
        }
    }
}

// ---------------------------------------------------------------------------
// CSR construction. packed[n] (u32) = (count << 24) | fixedpoint16(sum ew).
// Atomic return yields this edge's per-dst rank (stored coalesced) so fill
// needs NO atomic. Bit budget: in-degree << 255; sum ew < 256 so sum*2^16 <
// 2^24 — fields never collide. hist is bound by returned-atomic throughput
// (~19.5G/s measured R10-R12; LDS-chunked alternative regressed in R13 due
// to 100KB-LDS occupancy collapse).
// ---------------------------------------------------------------------------
__global__ void hist_kernel(const int* __restrict__ dst, const float* __restrict__ ew,
                            unsigned* __restrict__ packed,
                            int* __restrict__ rank, int E)
{
    int e = blockIdx.x * blockDim.x + threadIdx.x;
    if (e < E) {
        int d = dst[e];
        unsigned v = (1u << 24) | (unsigned)__float2uint_rn(ew[e] * 65536.f);
        unsigned old = atomicAdd(&packed[d], v);
        rank[e] = (int)(old >> 24);
    }
}

// ---------------------------------------------------------------------------
// fused scan: block b sums PADDED counts of all indices < b*1024 (coalesced),
// then local Hillis-Steele scan. Row segments are padded to a multiple of 8
// edges so gather's inner loop needs no bounds logic (pad slots are zeroed
// by init_prep; fill writes ranks 0..cnt-1 into the first cnt slots).
// Also computes dinv = rsqrt(1 + sum ew).
// ---------------------------------------------------------------------------
__global__ __launch_bounds__(SCAN_B) void scan_kernel(const unsigned* __restrict__ packed,
                                                      int* __restrict__ rowstart,
                                                      float* __restrict__ dinv, int N)
{
    __shared__ int red[SCAN_B];
    __shared__ int sdata[SCAN_B];
    const int t = threadIdx.x;
    const int base = blockIdx.x * SCAN_B;

    int pre = 0;
    for (int i = t; i < base; i += SCAN_B) pre += ((int)(packed[i] >> 24) + 7) & ~7;
    red[t] = pre;
    __syncthreads();
    for (int s = SCAN_B / 2; s > 0; s >>= 1) {
        if (t < s) red[t] += red[t + s];
        __syncthreads();
    }
    const int off0 = red[0];

    const int idx = base + t;
    const unsigned pk = (idx < N) ? packed[idx] : 0u;
    const int v = (((int)(pk >> 24)) + 7) & ~7;   // padded count
    sdata[t] = v;
    __syncthreads();
    for (int off = 1; off < SCAN_B; off <<= 1) {
        int tmp = (t >= off) ? sdata[t - off] : 0;
        __syncthreads();
        sdata[t] += tmp;
        __syncthreads();
    }
    const int incl = sdata[t];
    if (idx < N) {
        rowstart[idx] = off0 + incl - v;
        float deg = 1.0f + (float)(pk & 0xFFFFFFu) * (1.0f / 65536.0f);
        dinv[idx] = rsqrtf(deg);   // deg >= 1 always (self loop)
    }
    if (idx == N - 1) rowstart[N] = off0 + incl;
}

// ---------------------------------------------------------------------------
// scatter edges into CSR slots — atomic-free: pos = rowstart[dst] + rank[e].
// Single dispatch (R14 A/B: beat the 8x XCD-affine split by ~15us).
// pk.x = byte offset of bf16 row (96B). Pad slots beyond cnt stay zero.
// ---------------------------------------------------------------------------
__global__ void fill_kernel(const int* __restrict__ src, const int* __restrict__ dst,
                            const float* __restrict__ ew, const float* __restrict__ dinv,
                            const int* __restrict__ rowstart, const int* __restrict__ rank,
                            int2* __restrict__ edges, int E)
{
    int e = blockIdx.x * blockDim.x + threadIdx.x;
    if (e >= E) return;
    int d = dst[e];
    int s = src[e];
    int pos = rowstart[d] + rank[e];
    int2 pk;
    pk.x = s * (FP * 2);                       // byte offset of bf16 x row
    pk.y = __float_as_int(dinv[s] * ew[e]);
    edges[pos] = pk;
}

// ---------------------------------------------------------------------------
// fused gather + node kernel: one wave per dst node.
// Gather: 8 edge slots x 8 lanes (slot = lane>>3, q = lane&7); q<6 lanes load
// the slot's bf16 row as int4 (16B = 8 bf16, 6*8 = 48 elems exactly). Row
// segments padded to multiples of 8 (pad: w=0, off=0 -> L2-hot row 0) =>
// NO bounds logic in the inner loop: every lane runs exactly (end-beg)/8
// iterations. Cross-slot reduce via per-wave LDS (8 partials). Node phase:
// LDS b128 broadcasts + rcp gates (rel err ~2e-7); fp32 self-loop.
// ---------------------------------------------------------------------------
__global__ __launch_bounds__(256) void gather_node_kernel(
    const unsigned short* __restrict__ xs, const float* __restrict__ x,
    const int* __restrict__ rowstart,
    const int2* __restrict__ edges, const float* __restrict__ dinv,
    const float* __restrict__ probs,
    const float* __restrict__ Mz, const float* __restrict__ cz,
    const float* __restrict__ Mh, const float* __restrict__ ch,
    const float* __restrict__ Wc, const float* __restrict__ bc,
    float* __restrict__ out, int N)
{
    __shared__ __align__(16) float sWc[HID * FP];
    __shared__ __align__(16) float sprobs[16];
    __shared__ __align__(16) float yacc[4][384];  // per-wave 8-slot partials (8*48)
    __shared__ __align__(16) float yld[4][FP];    // per-wave, period-major (p*4+f)
    __shared__ __align__(16) float hld[4][HID];   // per-wave hidden vector
    for (int i = threadIdx.x; i < HID * FP; i += 256) sWc[i] = Wc[i];
    if (threadIdx.x < NP) sprobs[threadIdx.x] = probs[threadIdx.x];
    __syncthreads();

    const int lane = threadIdx.x & 63;
    const int wib  = threadIdx.x >> 6;
    const int n    = blockIdx.x * 4 + wib;
    if (n >= N) return;

    const int slot = lane >> 3;            // 0..7
    const int q    = lane & 7;             // 0..7; q<6 active for row loads
    const bool act = (q < 6);
    const int qc   = act ? q : 5;          // clamp keeps loads in-bounds
    const char* xsb = (const char*)xs;

    const int beg = rowstart[n];           // multiple of 8
    const int end = rowstart[n + 1];       // multiple of 8

    float a0 = 0.f, a1 = 0.f, a2 = 0.f, a3 = 0.f;
    float a4 = 0.f, a5 = 0.f, a6 = 0.f, a7 = 0.f;
    #pragma unroll 2
    for (int e = beg + slot; e < end; e += 8) {
        const int2 pk = edges[e];                       // pad slots: {0, 0}
        const float w = __int_as_float(pk.y);
        const int4 xv = *reinterpret_cast<const int4*>(xsb + pk.x + (qc << 4));
        a0 += w * __uint_as_float((unsigned)xv.x << 16);
        a1 += w * __uint_as_float((unsigned)xv.x & 0xffff0000u);
        a2 += w * __uint_as_float((unsigned)xv.y << 16);
        a3 += w * __uint_as_float((unsigned)xv.y & 0xffff0000u);
        a4 += w * __uint_as_float((unsigned)xv.z << 16);
        a5 += w * __uint_as_float((unsigned)xv.z & 0xffff0000u);
        a6 += w * __uint_as_float((unsigned)xv.w << 16);
        a7 += w * __uint_as_float((unsigned)xv.w & 0xffff0000u);
    }

    // stash 8 consecutive row elems per active lane: yacc[wib][slot*48 + q*8]
    if (act) {
        float* dst0 = &yacc[wib][slot * 48 + q * 8];
        float4 v0 = make_float4(a0, a1, a2, a3);
        float4 v1 = make_float4(a4, a5, a6, a7);
        *reinterpret_cast<float4*>(dst0)     = v0;
        *reinterpret_cast<float4*>(dst0 + 4) = v1;
    }

    // lane l (<48) owns row float l: sum 8 slot partials, add self-loop, norm
    const float di = dinv[n];
    if (lane < FP) {
        const float* yf = yacc[wib];
        float s = 0.f;
        #pragma unroll
        for (int sl = 0; sl < 8; ++sl) s += yf[sl * 48 + lane];
        float xself = x[(size_t)n * FP + lane];      // fp32 self-loop (exact)
        float yv = di * s + di * di * xself;
        int f = lane / 12;
        int p = lane - f * 12;
        yld[wib][p * 4 + f] = yv;                    // period-major stash
    }

    // ---- node phase (lane = hidden dim) ----
    const float mz0 = Mz[lane], mz1 = Mz[64 + lane], mz2 = Mz[128 + lane], mz3 = Mz[192 + lane];
    const float mh0 = Mh[lane], mh1 = Mh[64 + lane], mh2 = Mh[128 + lane], mh3 = Mh[192 + lane];
    const float czv = cz[lane], chv = ch[lane];
    const int   c   = (lane < FP) ? lane : 0;
    const float bcv = bc[c];

    const float* yw = yld[wib];
    float hacc = 0.f;
    #pragma unroll
    for (int p = 0; p < NP; ++p) {
        const float4 v = *reinterpret_cast<const float4*>(yw + p * 4);
        float az = czv + v.x * mz0 + v.y * mz1 + v.z * mz2 + v.w * mz3;
        float ah = chv + v.x * mh0 + v.y * mh1 + v.z * mh2 + v.w * mh3;
        float g  = __builtin_amdgcn_rcpf(1.f + __expf(az));
        float ahc = fminf(fmaxf(ah, -15.f), 15.f);
        float eh = __expf(2.f * ahc);
        float th = 1.f - 2.f * __builtin_amdgcn_rcpf(eh + 1.f);
        hacc += sprobs[p] * g * th;
    }
    hacc = fmaxf(hacc, 0.f);

    hld[wib][lane] = hacc;
    const float* hw = hld[wib];
    float o = bcv;
    #pragma unroll
    for (int i4 = 0; i4 < 16; ++i4) {
        const float4 h4 = *reinterpret_cast<const float4*>(hw + i4 * 4);
        o += h4.x * sWc[(i4 * 4 + 0) * FP + c];
        o += h4.y * sWc[(i4 * 4 + 1) * FP + c];
        o += h4.z * sWc[(i4 * 4 + 2) * FP + c];
        o += h4.w * sWc[(i4 * 4 + 3) * FP + c];
    }
    if (lane < FP) out[(size_t)n * FP + lane] = o;
}

// ---------------------------------------------------------------------------
extern "C" void kernel_launch(void* const* d_in, const int* in_sizes, int n_in,
                              void* d_out, int out_size, void* d_ws, size_t ws_size,
                              hipStream_t stream)
{
    const int N = in_sizes[0] / FP;   // 50000
    const int E = in_sizes[1] / 2;    // 1.6M
    const int NB = (N + SCAN_B - 1) / SCAN_B;
    const int Epad = E + 8 * N + 16;  // per-row pad to multiple of 8 (max +7/row)

    const float* x    = (const float*)d_in[0];
    const int*   ei   = (const int*)d_in[1];
    const float* ew   = (const float*)d_in[2];
    const float* att  = (const float*)d_in[3];
    const float* Wg_z = (const float*)d_in[4];
    const float* bg_z = (const float*)d_in[5];
    const float* Wl_z = (const float*)d_in[6];
    const float* bl_z = (const float*)d_in[7];
    // d_in[8..11] = r-gate params: unused (H=0 => Hz*r = 0)
    const float* Wg_h = (const float*)d_in[12];
    const float* bg_h = (const float*)d_in[13];
    const float* Wl_h = (const float*)d_in[14];
    const float* bl_h = (const float*)d_in[15];
    const float* W1 = (const float*)d_in[16]; const float* b1 = (const float*)d_in[17];
    const float* W2 = (const float*)d_in[18]; const float* b2 = (const float*)d_in[19];
    const float* W3 = (const float*)d_in[20]; const float* b3 = (const float*)d_in[21];
    const float* W4 = (const float*)d_in[22]; const float* b4 = (const float*)d_in[23];
    const float* Wo = (const float*)d_in[24]; const float* bo = (const float*)d_in[25];

    const int* srcp = ei;
    const int* dstp = ei + E;

    // workspace layout (8B-aligned items first) — ~28 MB of 256 MiB ws
    int2*  edges    = (int2*)d_ws;                                       // Epad
    unsigned short* xs = (unsigned short*)(edges + Epad);                // N*FP bf16
    unsigned* packed= (unsigned*)(xs + (size_t)N * FP);                  // N (u32)
    int*   rank     = (int*)(packed + N);                                // E
    float* dinv     = (float*)(rank + E);                                // N
    int*   rowstart = (int*)(dinv + N);                                  // N+1
    float* probs    = (float*)(rowstart + N + 1 + 63);                   // 16 (padded)
    float* Mz       = probs + 16;                                        // 256
    float* cz       = Mz + 256;                                          // 64
    float* Mh       = cz + 64;                                           // 256
    float* ch       = Mh + 256;                                          // 64
    float* Wc       = ch + 64;                                           // 3072
    float* bc       = Wc + HID * FP;                                     // 48

    const int initBlocks = (N + 255) / 256;
    init_prep_kernel<<<initBlocks + 1, 256, 0, stream>>>(
        att, Wg_z, bg_z, Wl_z, bl_z, Wg_h, bg_h, Wl_h, bl_h,
        W1, b1, W2, b2, W3, b3, W4, b4, Wo, bo,
        probs, Mz, cz, Mh, ch, Wc, bc,
        packed, edges, Epad, x, xs, N, initBlocks);

    hist_kernel<<<(E + 255) / 256, 256, 0, stream>>>(dstp, ew, packed, rank, E);
    scan_kernel<<<NB, SCAN_B, 0, stream>>>(packed, rowstart, dinv, N);
    fill_kernel<<<(E + 255) / 256, 256, 0, stream>>>(srcp, dstp, ew, dinv, rowstart, rank, edges, E);

    gather_node_kernel<<<(N + 3) / 4, 256, 0, stream>>>(xs, x, rowstart, edges, dinv,
                                                        probs, Mz, cz, Mh, ch, Wc, bc,
                                                        (float*)d_out, N);
}